// Round 1
// baseline (2455.117 us; speedup 1.0000x reference)
//
#include <hip/hip_runtime.h>

// Swin window attention, fp32 baseline.
// B=8, DM=768, NH=12, HD=64, H=W=64, WS=8 -> 512 windows x 64 tokens.
// Workspace: Q,K,V (each [512][12][64][64] f32) + Obuf ([32768][768] f32)
//          = 4 * 25165824 * 4 B = 402,653,184 bytes.

#define DM      768
#define NHEADS  12
#define HD      64
#define LTOK    64
#define NWIN    512

// ---------------------------------------------------------------------------
// Kernel 1: fused window-gather + QKV projection.
// grid (512, 18): x = window, y = 128-col tile over concat [Wq|Wk|Wv] (3*6).
// block 256. Tile: 64 tokens x 128 outputs, BK=16, 4x8 acc per thread.
// Q is written pre-scaled by 1/8 (= 1/SCALE).
// ---------------------------------------------------------------------------
__global__ __launch_bounds__(256)
void qkv_kernel(const float* __restrict__ x,
                const float* __restrict__ Wq,
                const float* __restrict__ Wk,
                const float* __restrict__ Wv,
                float* __restrict__ Q,
                float* __restrict__ K,
                float* __restrict__ V)
{
    const int win   = blockIdx.x;
    const int yt    = blockIdx.y;          // 0..17
    const int mat   = yt / 6;              // 0=q 1=k 2=v
    const int ntile = yt % 6;              // 128-col tile within 768

    const float* __restrict__ Wm = (mat == 0) ? Wq : (mat == 1) ? Wk : Wv;
    float* __restrict__ Out      = (mat == 0) ? Q  : (mat == 1) ? K  : V;
    const float scale = (mat == 0) ? 0.125f : 1.0f;

    const int b  = win >> 6;
    const int wh = (win >> 3) & 7;
    const int ww = win & 7;

    const int tid = threadIdx.x;
    const int tx  = tid & 15;              // output-col group (8 cols)
    const int ty  = tid >> 4;              // token-row group (4 rows)

    // stride 68 / 132: keeps float4 LDS reads 16B-aligned; bank-friendly.
    __shared__ float As[16][68];           // [k][token]
    __shared__ float Bs[16][132];          // [k][out-col]

    float acc[4][8];
#pragma unroll
    for (int i = 0; i < 4; ++i)
#pragma unroll
        for (int j = 0; j < 8; ++j) acc[i][j] = 0.0f;

    // A-load mapping: lane -> token, tid>>6 -> k-sub
    const int la  = tid & 63;
    const int ca0 = tid >> 6;              // 0..3
    const int h   = wh * 8 + (la >> 3);
    const int w   = ww * 8 + (la & 7);
    const int xbase = (b * DM) * 4096 + h * 64 + w;   // + c*4096

    // B-load mapping
    const int cb  = tid & 15;
    const int ob0 = tid >> 4;              // 0..15
    const int obase = ntile * 128;

    for (int kt = 0; kt < DM; kt += 16) {
#pragma unroll
        for (int r = 0; r < 4; ++r) {
            const int c = kt + ca0 + r * 4;
            As[ca0 + r * 4][la] = x[xbase + c * 4096];
        }
#pragma unroll
        for (int r = 0; r < 8; ++r) {
            const int o = ob0 + r * 16;
            Bs[cb][o] = Wm[(obase + o) * DM + kt + cb];
        }
        __syncthreads();
#pragma unroll
        for (int kk = 0; kk < 16; ++kk) {
            const float4 a4  = *(const float4*)&As[kk][ty * 4];
            const float4 b40 = *(const float4*)&Bs[kk][tx * 8];
            const float4 b41 = *(const float4*)&Bs[kk][tx * 8 + 4];
            const float a[4]  = {a4.x, a4.y, a4.z, a4.w};
            const float bb[8] = {b40.x, b40.y, b40.z, b40.w,
                                 b41.x, b41.y, b41.z, b41.w};
#pragma unroll
            for (int i = 0; i < 4; ++i)
#pragma unroll
                for (int j = 0; j < 8; ++j)
                    acc[i][j] += a[i] * bb[j];
        }
        __syncthreads();
    }

    // write: layout [win][head][l][d]; cols of this thread stay in one head
    const int c0   = obase + tx * 8;
    const int head = c0 >> 6;
    const int d0   = c0 & 63;
    float* dst0 = Out + ((win * NHEADS + head) * LTOK) * HD + d0;
#pragma unroll
    for (int i = 0; i < 4; ++i) {
        const int l = ty * 4 + i;
        float4 v0 = make_float4(acc[i][0]*scale, acc[i][1]*scale,
                                acc[i][2]*scale, acc[i][3]*scale);
        float4 v1 = make_float4(acc[i][4]*scale, acc[i][5]*scale,
                                acc[i][6]*scale, acc[i][7]*scale);
        *(float4*)(dst0 + l * HD)     = v0;
        *(float4*)(dst0 + l * HD + 4) = v1;
    }
}

// ---------------------------------------------------------------------------
// Kernel 2: attention per (window, head). grid (512, 12), block 256.
// S = q k^T (q pre-scaled) + bias; softmax over m; O = P V.
// 4x4 outputs/thread; row-softmax via 16-lane shfl groups.
// ---------------------------------------------------------------------------
__global__ __launch_bounds__(256)
void attn_kernel(const float* __restrict__ Q,
                 const float* __restrict__ K,
                 const float* __restrict__ V,
                 const float* __restrict__ rpb,     // [12][225]
                 const int*   __restrict__ coords,  // [64][64]
                 float* __restrict__ Obuf)          // [32768][768]
{
    const int win  = blockIdx.x;
    const int head = blockIdx.y;
    const int tid  = threadIdx.x;
    const int tx = tid & 15, ty = tid >> 4;

    __shared__ float qs[64][65];   // +1 pad: hot scalar reads are <=2-way
    __shared__ float ks[64][65];
    __shared__ float vs[64][65];

    const int base = (win * NHEADS + head) * (LTOK * HD);

#pragma unroll
    for (int r = 0; r < 4; ++r) {
        const int f = tid + r * 256;          // float4 index 0..1023
        const int e = f * 4;
        const int l = e >> 6, d = e & 63;
        float4 t;
        t = *(const float4*)(Q + base + e);
        qs[l][d] = t.x; qs[l][d+1] = t.y; qs[l][d+2] = t.z; qs[l][d+3] = t.w;
        t = *(const float4*)(K + base + e);
        ks[l][d] = t.x; ks[l][d+1] = t.y; ks[l][d+2] = t.z; ks[l][d+3] = t.w;
        t = *(const float4*)(V + base + e);
        vs[l][d] = t.x; vs[l][d+1] = t.y; vs[l][d+2] = t.z; vs[l][d+3] = t.w;
    }
    __syncthreads();

    float acc[4][4];
#pragma unroll
    for (int i = 0; i < 4; ++i)
#pragma unroll
        for (int j = 0; j < 4; ++j) acc[i][j] = 0.0f;

    for (int d = 0; d < HD; ++d) {
        float a[4], bb[4];
#pragma unroll
        for (int i = 0; i < 4; ++i) a[i]  = qs[ty*4+i][d];
#pragma unroll
        for (int j = 0; j < 4; ++j) bb[j] = ks[tx*4+j][d];
#pragma unroll
        for (int i = 0; i < 4; ++i)
#pragma unroll
            for (int j = 0; j < 4; ++j) acc[i][j] += a[i] * bb[j];
    }

    // + relative-position bias (gathers hit L2; tables are tiny)
#pragma unroll
    for (int i = 0; i < 4; ++i) {
        const int l = ty*4 + i;
#pragma unroll
        for (int j = 0; j < 4; ++j) {
            const int m = tx*4 + j;
            acc[i][j] += rpb[head * 225 + coords[l * 64 + m]];
        }
    }

    // softmax over m: rows owned by 16 consecutive lanes (same wave)
    float inv[4];
#pragma unroll
    for (int i = 0; i < 4; ++i) {
        float mx = fmaxf(fmaxf(acc[i][0], acc[i][1]),
                         fmaxf(acc[i][2], acc[i][3]));
#pragma unroll
        for (int off = 1; off < 16; off <<= 1)
            mx = fmaxf(mx, __shfl_xor(mx, off));
        float s = 0.0f;
#pragma unroll
        for (int j = 0; j < 4; ++j) {
            acc[i][j] = expf(acc[i][j] - mx);
            s += acc[i][j];
        }
#pragma unroll
        for (int off = 1; off < 16; off <<= 1)
            s += __shfl_xor(s, off);
        inv[i] = 1.0f / s;
    }

    __syncthreads();                       // all reads of qs done
#pragma unroll
    for (int i = 0; i < 4; ++i)
#pragma unroll
        for (int j = 0; j < 4; ++j)
            qs[ty*4+i][tx*4+j] = acc[i][j] * inv[i];   // P reuses qs
    __syncthreads();

    float o[4][4];
#pragma unroll
    for (int i = 0; i < 4; ++i)
#pragma unroll
        for (int j = 0; j < 4; ++j) o[i][j] = 0.0f;

    for (int m = 0; m < LTOK; ++m) {
        float a[4], bb[4];
#pragma unroll
        for (int i = 0; i < 4; ++i) a[i]  = qs[ty*4+i][m];
#pragma unroll
        for (int j = 0; j < 4; ++j) bb[j] = vs[m][tx*4+j];
#pragma unroll
        for (int i = 0; i < 4; ++i)
#pragma unroll
            for (int j = 0; j < 4; ++j) o[i][j] += a[i] * bb[j];
    }

    // Obuf token-major: [win*64 + l][head*64 + d]
    float* dst = Obuf + (size_t)(win * LTOK) * DM + head * HD;
#pragma unroll
    for (int i = 0; i < 4; ++i) {
        const int l = ty*4 + i;
        *(float4*)(dst + l * DM + tx * 4) =
            make_float4(o[i][0], o[i][1], o[i][2], o[i][3]);
    }
}

// ---------------------------------------------------------------------------
// Kernel 3: output projection + bias, scatter to (B, C, H, W).
// grid (512, 6): x = window, y = 128-col tile. Same GEMM tile as kernel 1.
// ---------------------------------------------------------------------------
__global__ __launch_bounds__(256)
void outproj_kernel(const float* __restrict__ Obuf,
                    const float* __restrict__ Wo,
                    const float* __restrict__ Wb,
                    float* __restrict__ out)
{
    const int win = blockIdx.x;
    const int nt  = blockIdx.y;            // 0..5
    const int b  = win >> 6;
    const int wh = (win >> 3) & 7;
    const int ww = win & 7;

    const int tid = threadIdx.x;
    const int tx = tid & 15, ty = tid >> 4;

    __shared__ float As[16][68];
    __shared__ float Bs[16][132];

    float acc[4][8];
#pragma unroll
    for (int i = 0; i < 4; ++i)
#pragma unroll
        for (int j = 0; j < 8; ++j) acc[i][j] = 0.0f;

    const int cb  = tid & 15;
    const int lb0 = tid >> 4;              // token row for A loads
    const int ob0 = tid >> 4;
    const int obase = nt * 128;

    for (int kt = 0; kt < DM; kt += 16) {
#pragma unroll
        for (int r = 0; r < 4; ++r) {
            const int l = lb0 + r * 16;
            As[cb][l] = Obuf[(size_t)(win * LTOK + l) * DM + kt + cb];
        }
#pragma unroll
        for (int r = 0; r < 8; ++r) {
            const int o = ob0 + r * 16;
            Bs[cb][o] = Wo[(obase + o) * DM + kt + cb];
        }
        __syncthreads();
#pragma unroll
        for (int kk = 0; kk < 16; ++kk) {
            const float4 a4  = *(const float4*)&As[kk][ty * 4];
            const float4 b40 = *(const float4*)&Bs[kk][tx * 8];
            const float4 b41 = *(const float4*)&Bs[kk][tx * 8 + 4];
            const float a[4]  = {a4.x, a4.y, a4.z, a4.w};
            const float bb[8] = {b40.x, b40.y, b40.z, b40.w,
                                 b41.x, b41.y, b41.z, b41.w};
#pragma unroll
            for (int i = 0; i < 4; ++i)
#pragma unroll
                for (int j = 0; j < 8; ++j)
                    acc[i][j] += a[i] * bb[j];
        }
        __syncthreads();
    }

    // rows l = ty*4+0..3 share h; w contiguous -> float4 along w per output o
    const int iw    = ty >> 1;
    const int jw0   = (ty & 1) * 4;
    const int hrow  = wh * 8 + iw;
    const int wcol0 = ww * 8 + jw0;
#pragma unroll
    for (int j = 0; j < 8; ++j) {
        const int o = obase + tx * 8 + j;
        const float bias = Wb[o];
        float4 t = make_float4(acc[0][j] + bias, acc[1][j] + bias,
                               acc[2][j] + bias, acc[3][j] + bias);
        *(float4*)(out + ((size_t)(b * DM + o) * 64 + hrow) * 64 + wcol0) = t;
    }
}

// ---------------------------------------------------------------------------
extern "C" void kernel_launch(void* const* d_in, const int* in_sizes, int n_in,
                              void* d_out, int out_size, void* d_ws, size_t ws_size,
                              hipStream_t stream)
{
    const float* x   = (const float*)d_in[0];
    const float* Wq  = (const float*)d_in[1];
    const float* Wk  = (const float*)d_in[2];
    const float* Wv  = (const float*)d_in[3];
    const float* Wo  = (const float*)d_in[4];
    const float* Wb  = (const float*)d_in[5];
    const float* rpb = (const float*)d_in[6];
    const int*   rc  = (const int*)d_in[7];
    float* out = (float*)d_out;

    const size_t TSZ = (size_t)NWIN * NHEADS * LTOK * HD;   // 25,165,824
    float* Q    = (float*)d_ws;
    float* K    = Q + TSZ;
    float* V    = K + TSZ;
    float* Obuf = V + TSZ;   // needs ws_size >= 4*TSZ*4 = 402,653,184 B

    qkv_kernel    <<<dim3(NWIN, 18), 256, 0, stream>>>(x, Wq, Wk, Wv, Q, K, V);
    attn_kernel   <<<dim3(NWIN, NHEADS), 256, 0, stream>>>(Q, K, V, rpb, rc, Obuf);
    outproj_kernel<<<dim3(NWIN, 6), 256, 0, stream>>>(Obuf, Wo, Wb, out);
}

// Round 6
// 899.791 us; speedup vs baseline: 2.7285x; 2.7285x over previous
//
#include <hip/hip_runtime.h>

// Swin window attention, split-bf16 MFMA GEMMs + fp32 attention core.
// B=8, DM=768, NH=12, HD=64, H=W=64, WS=8 -> 512 windows x 64 tokens, M=32768.
//
// Pipeline:
//   xprep       : gather x (B,C,H,W) -> Xw[token][c] split into bf16 hi/lo
//   fsplit x3   : [Wq;Wk;Wv] -> bf16 hi/lo  (scratch = d_out, dead until outproj)
//   qkv_mfma    : [32768x768]x[768x2304], 3-term split-bf16 MFMA -> Q,K,V fp32
//   attn        : per (window,head) fp32 attention -> Obuf bf16 hi/lo (alias X)
//   fsplit (Wo) : Wo -> bf16 hi/lo into Q region (Q dead after attn)
//   outproj     : [32768x768]x[768x768] split-bf16 MFMA + bias -> out (B,C,H,W)
//
// d_ws usage (= Round-1-proven 402,653,184 B, never exceeded):
//   [0,          100663296) Xhi|Xlo  (later Obuf hi|lo)
//   [100663296,  402653184) Q | K | V fp32  (Wo splits alias Q after attn)
// d_out doubles as scratch for the QKV W-splits (7,077,888 B) until outproj.

#define DM      768
#define NHEADS  12
#define HD      64
#define LTOK    64
#define NWIN    512

typedef __attribute__((ext_vector_type(8))) short bf16x8;
typedef __attribute__((ext_vector_type(4))) float f32x4;

__device__ __forceinline__ unsigned short f2bf(float f) {
    union { float f; unsigned u; } v; v.f = f;
    unsigned r = v.u + 0x7FFFu + ((v.u >> 16) & 1u);   // RNE
    return (unsigned short)(r >> 16);
}
__device__ __forceinline__ float bf2f(unsigned short h) {
    union { unsigned u; float f; } v; v.u = ((unsigned)h) << 16;
    return v.f;
}
__device__ __forceinline__ void gl_lds16(const void* g, void* l) {
    __builtin_amdgcn_global_load_lds(
        (const __attribute__((address_space(1))) void*)g,
        (__attribute__((address_space(3))) void*)l, 16, 0, 0);
}

// ---------------------------------------------------------------------------
// xprep: 32c x 32px transpose tiles. Read x coalesced (128B rows), write
// Xhi/Xlo[token][c] in 64B segments. grid (128 pxtile, 24 ctile, 8 b).
// ---------------------------------------------------------------------------
__global__ __launch_bounds__(256)
void xprep_kernel(const float* __restrict__ x,
                  unsigned short* __restrict__ Xhi,
                  unsigned short* __restrict__ Xlo)
{
    __shared__ float lds[32][33];
    const int tid = threadIdx.x;
    const int px0 = blockIdx.x * 32;
    const int c0  = blockIdx.y * 32;
    const int b   = blockIdx.z;
    {
        const int cc = tid >> 3, w4 = tid & 7;
        const float4 v = *(const float4*)(
            x + ((size_t)(b * DM + c0 + cc)) * 4096 + px0 + w4 * 4);
        lds[cc][w4*4+0] = v.x; lds[cc][w4*4+1] = v.y;
        lds[cc][w4*4+2] = v.z; lds[cc][w4*4+3] = v.w;
    }
    __syncthreads();
    const int tpx = tid >> 3, cg = tid & 7;
    const int p = px0 + tpx, h = p >> 6, w = p & 63;
    const int t = (((b << 6) | ((h >> 3) << 3) | (w >> 3)) << 6)
                | ((h & 7) << 3) | (w & 7);
    const size_t dst = (size_t)t * DM + c0 + cg * 4;
    const float f0 = lds[cg*4+0][tpx], f1 = lds[cg*4+1][tpx],
                f2 = lds[cg*4+2][tpx], f3 = lds[cg*4+3][tpx];
    ushort4 hv, lv;
    hv.x = f2bf(f0); lv.x = f2bf(f0 - bf2f(hv.x));
    hv.y = f2bf(f1); lv.y = f2bf(f1 - bf2f(hv.y));
    hv.z = f2bf(f2); lv.z = f2bf(f2 - bf2f(hv.z));
    hv.w = f2bf(f3); lv.w = f2bf(f3 - bf2f(hv.w));
    *(ushort4*)(Xhi + dst) = hv;
    *(ushort4*)(Xlo + dst) = lv;
}

// ---------------------------------------------------------------------------
__global__ __launch_bounds__(256)
void fsplit_kernel(const float* __restrict__ src,
                   unsigned short* __restrict__ hi,
                   unsigned short* __restrict__ lo, int n)
{
    const int i = (blockIdx.x * 256 + threadIdx.x) * 4;
    if (i >= n) return;
    const float4 v = *(const float4*)(src + i);
    ushort4 hv, lv;
    hv.x = f2bf(v.x); lv.x = f2bf(v.x - bf2f(hv.x));
    hv.y = f2bf(v.y); lv.y = f2bf(v.y - bf2f(hv.y));
    hv.z = f2bf(v.z); lv.z = f2bf(v.z - bf2f(hv.z));
    hv.w = f2bf(v.w); lv.w = f2bf(v.w - bf2f(hv.w));
    *(ushort4*)(hi + i) = hv;
    *(ushort4*)(lo + i) = lv;
}

// ---------------------------------------------------------------------------
// Split-bf16 MFMA GEMM, m97 structure. 128x128 tile, BK=32, 4 waves (2x2),
// wave tile 64x64 = 4x4 frags of 16x16x32. LDS linear [128 rows][4 chunks
// of 16B], staged via global_load_lds with source-side XOR swizzle
// chunk ^= ((row&15)>>1)&3; fragment ds_read_b128 applies the same XOR ->
// 2-way banks (free). Tiles: Ahi@0 Alo@8192 Bhi@16384 Blo@24576 (8KB each).
// Fragment maps (m89-verified family):
//   A: lane l -> A[l&15][8*(l>>4)+j]   B: lane l -> B[8*(l>>4)+j][l&15]
//   D: lane l, reg q -> D[4*(l>>4)+q][l&15]
// ---------------------------------------------------------------------------
#define GEMM_PROLOGUE(AHIP, ALOP, BHIP, BLOP)                                  \
    __shared__ f32x4 smem4[2048];           /* 32 KB, 16B-aligned */           \
    char* const smem = (char*)smem4;                                           \
    const int tid  = threadIdx.x;                                              \
    const int lane = tid & 63, wv = tid >> 6;                                  \
    const int wr = wv >> 1, wc = wv & 1;                                       \
    const int nt = blockIdx.x;                                                 \
    const int m0 = blockIdx.y * 128;                                           \
    const int n0 = nt * 128;                                                   \
    const int rql = lane >> 2;                                                 \
    const int gsw = (lane & 3) ^ ((lane >> 3) & 3);                            \
    const char* gb0 = (const char*)(AHIP) + (size_t)m0 * 1536;                 \
    const char* gb1 = (const char*)(ALOP) + (size_t)m0 * 1536;                 \
    const char* gb2 = (const char*)(BHIP) + (size_t)n0 * 1536;                 \
    const char* gb3 = (const char*)(BLOP) + (size_t)n0 * 1536;                 \
    const int l15 = lane & 15, kg = lane >> 4;                                 \
    const int kgp = kg ^ ((l15 >> 1) & 3);                                     \
    int aoff[4], boff[4];                                                      \
    _Pragma("unroll")                                                          \
    for (int f = 0; f < 4; ++f) {                                              \
        aoff[f] = (wr * 64 + f * 16 + l15) * 64 + kgp * 16;                    \
        boff[f] = (wc * 64 + f * 16 + l15) * 64 + kgp * 16;                    \
    }                                                                          \
    f32x4 acc[4][4];                                                           \
    _Pragma("unroll")                                                          \
    for (int i = 0; i < 4; ++i)                                                \
        _Pragma("unroll")                                                      \
        for (int j = 0; j < 4; ++j) acc[i][j] = (f32x4){0.f, 0.f, 0.f, 0.f};   \
    _Pragma("unroll 1")                                                        \
    for (int kt = 0; kt < DM; kt += 32) {                                      \
        const size_t kb = (size_t)kt * 2;                                      \
        _Pragma("unroll")                                                      \
        for (int q = 0; q < 8; ++q) {                                          \
            const int tt = q >> 1;                                             \
            const int s  = wv * 2 + (q & 1);                                   \
            const int r  = s * 16 + rql;                                       \
            const char* srcp = (tt == 0 ? gb0 : tt == 1 ? gb1 :                \
                                tt == 2 ? gb2 : gb3)                           \
                               + (size_t)r * 1536 + kb + gsw * 16;             \
            gl_lds16(srcp, smem + tt * 8192 + s * 1024);                       \
        }                                                                      \
        __syncthreads();                                                       \
        bf16x8 ah[4], al[4], bh[4], bl[4];                                     \
        _Pragma("unroll")                                                      \
        for (int f = 0; f < 4; ++f) {                                          \
            ah[f] = *(const bf16x8*)(smem +     0 + aoff[f]);                  \
            al[f] = *(const bf16x8*)(smem +  8192 + aoff[f]);                  \
            bh[f] = *(const bf16x8*)(smem + 16384 + boff[f]);                  \
            bl[f] = *(const bf16x8*)(smem + 24576 + boff[f]);                  \
        }                                                                      \
        _Pragma("unroll")                                                      \
        for (int mi = 0; mi < 4; ++mi)                                         \
            _Pragma("unroll")                                                  \
            for (int ni = 0; ni < 4; ++ni) {                                   \
                acc[mi][ni] = __builtin_amdgcn_mfma_f32_16x16x32_bf16(         \
                    ah[mi], bh[ni], acc[mi][ni], 0, 0, 0);                     \
                acc[mi][ni] = __builtin_amdgcn_mfma_f32_16x16x32_bf16(         \
                    ah[mi], bl[ni], acc[mi][ni], 0, 0, 0);                     \
                acc[mi][ni] = __builtin_amdgcn_mfma_f32_16x16x32_bf16(         \
                    al[mi], bh[ni], acc[mi][ni], 0, 0, 0);                     \
            }                                                                  \
        __syncthreads();                                                       \
    }

__global__ __launch_bounds__(256, 2)
void qkv_mfma_kernel(const unsigned short* __restrict__ Xhi,
                     const unsigned short* __restrict__ Xlo,
                     const unsigned short* __restrict__ Whi,
                     const unsigned short* __restrict__ Wlo,
                     float* __restrict__ Q, float* __restrict__ K,
                     float* __restrict__ V)
{
    GEMM_PROLOGUE(Xhi, Xlo, Whi, Wlo)

    // n = nt*128 + wc*64 + ni*16 + l15; mat = nt/6, head = (nt%6)*2+wc
    const int mat = nt / 6, c6 = nt % 6;
    float* __restrict__ Out = (mat == 0) ? Q : (mat == 1) ? K : V;
    const float scale = (mat == 0) ? 0.125f : 1.0f;   // 1/sqrt(64)
    const int head = c6 * 2 + wc;
#pragma unroll
    for (int mi = 0; mi < 4; ++mi) {
#pragma unroll
        for (int qq = 0; qq < 4; ++qq) {
            const int m   = m0 + wr * 64 + mi * 16 + kg * 4 + qq;
            const int win = m >> 6, tok = m & 63;
            float* rowp = Out + (size_t)win * 49152 + head * 4096 + tok * 64;
#pragma unroll
            for (int ni = 0; ni < 4; ++ni)
                rowp[ni * 16 + l15] = acc[mi][ni][qq] * scale;
        }
    }
}

__global__ __launch_bounds__(256, 2)
void outproj_mfma_kernel(const unsigned short* __restrict__ Ohi,
                         const unsigned short* __restrict__ Olo,
                         const unsigned short* __restrict__ Wohi,
                         const unsigned short* __restrict__ Wolo,
                         const float* __restrict__ Wb,
                         float* __restrict__ out)
{
    GEMM_PROLOGUE(Ohi, Olo, Wohi, Wolo)

    float bsv[4];
    int   ocol[4];
#pragma unroll
    for (int ni = 0; ni < 4; ++ni) {
        ocol[ni] = n0 + wc * 64 + ni * 16 + l15;
        bsv[ni]  = Wb[ocol[ni]];
    }
#pragma unroll
    for (int mi = 0; mi < 4; ++mi) {
#pragma unroll
        for (int qq = 0; qq < 4; ++qq) {
            const int m    = m0 + wr * 64 + mi * 16 + kg * 4 + qq;
            const int win  = m >> 6, tl = m & 63;
            const int bimg = win >> 6, wh = (win >> 3) & 7, ww = win & 7;
            const int h = wh * 8 + (tl >> 3), w = ww * 8 + (tl & 7);
            float* pix = out + (size_t)bimg * DM * 4096 + (size_t)h * 64 + w;
#pragma unroll
            for (int ni = 0; ni < 4; ++ni)
                pix[(size_t)ocol[ni] * 4096] = acc[mi][ni][qq] + bsv[ni];
        }
    }
}

// ---------------------------------------------------------------------------
// attention per (window, head), fp32. grid (512, 12), block 256.
// Output written as split bf16 into Obuf hi/lo [32768][768] (aliases X).
// ---------------------------------------------------------------------------
__global__ __launch_bounds__(256)
void attn_kernel(const float* __restrict__ Q,
                 const float* __restrict__ K,
                 const float* __restrict__ V,
                 const float* __restrict__ rpb,     // [12][225]
                 const int*   __restrict__ coords,  // [64][64]
                 unsigned short* __restrict__ Obhi,
                 unsigned short* __restrict__ Oblo)
{
    const int win  = blockIdx.x;
    const int head = blockIdx.y;
    const int tid  = threadIdx.x;
    const int tx = tid & 15, ty = tid >> 4;

    __shared__ float qs[64][65];
    __shared__ float ks[64][65];
    __shared__ float vs[64][65];

    const int base = (win * NHEADS + head) * (LTOK * HD);

#pragma unroll
    for (int r = 0; r < 4; ++r) {
        const int f = tid + r * 256;
        const int e = f * 4;
        const int l = e >> 6, d = e & 63;
        float4 t;
        t = *(const float4*)(Q + base + e);
        qs[l][d] = t.x; qs[l][d+1] = t.y; qs[l][d+2] = t.z; qs[l][d+3] = t.w;
        t = *(const float4*)(K + base + e);
        ks[l][d] = t.x; ks[l][d+1] = t.y; ks[l][d+2] = t.z; ks[l][d+3] = t.w;
        t = *(const float4*)(V + base + e);
        vs[l][d] = t.x; vs[l][d+1] = t.y; vs[l][d+2] = t.z; vs[l][d+3] = t.w;
    }
    __syncthreads();

    float acc[4][4];
#pragma unroll
    for (int i = 0; i < 4; ++i)
#pragma unroll
        for (int j = 0; j < 4; ++j) acc[i][j] = 0.0f;

    for (int d = 0; d < HD; ++d) {
        float a[4], bb[4];
#pragma unroll
        for (int i = 0; i < 4; ++i) a[i]  = qs[ty*4+i][d];
#pragma unroll
        for (int j = 0; j < 4; ++j) bb[j] = ks[tx*4+j][d];
#pragma unroll
        for (int i = 0; i < 4; ++i)
#pragma unroll
            for (int j = 0; j < 4; ++j) acc[i][j] += a[i] * bb[j];
    }

#pragma unroll
    for (int i = 0; i < 4; ++i) {
        const int l = ty*4 + i;
#pragma unroll
        for (int j = 0; j < 4; ++j)
            acc[i][j] += rpb[head * 225 + coords[l * 64 + tx*4 + j]];
    }

    float inv[4];
#pragma unroll
    for (int i = 0; i < 4; ++i) {
        float mx = fmaxf(fmaxf(acc[i][0], acc[i][1]),
                         fmaxf(acc[i][2], acc[i][3]));
#pragma unroll
        for (int off = 1; off < 16; off <<= 1)
            mx = fmaxf(mx, __shfl_xor(mx, off));
        float s = 0.0f;
#pragma unroll
        for (int j = 0; j < 4; ++j) {
            acc[i][j] = expf(acc[i][j] - mx);
            s += acc[i][j];
        }
#pragma unroll
        for (int off = 1; off < 16; off <<= 1)
            s += __shfl_xor(s, off);
        inv[i] = 1.0f / s;
    }

    __syncthreads();
#pragma unroll
    for (int i = 0; i < 4; ++i)
#pragma unroll
        for (int j = 0; j < 4; ++j)
            qs[ty*4+i][tx*4+j] = acc[i][j] * inv[i];
    __syncthreads();

    float o[4][4];
#pragma unroll
    for (int i = 0; i < 4; ++i)
#pragma unroll
        for (int j = 0; j < 4; ++j) o[i][j] = 0.0f;

    for (int m = 0; m < LTOK; ++m) {
        float a[4], bb[4];
#pragma unroll
        for (int i = 0; i < 4; ++i) a[i]  = qs[ty*4+i][m];
#pragma unroll
        for (int j = 0; j < 4; ++j) bb[j] = vs[m][tx*4+j];
#pragma unroll
        for (int i = 0; i < 4; ++i)
#pragma unroll
            for (int j = 0; j < 4; ++j) o[i][j] += a[i] * bb[j];
    }

    unsigned short* dh = Obhi + (size_t)(win * LTOK) * DM + head * HD + tx * 4;
    unsigned short* dl = Oblo + (size_t)(win * LTOK) * DM + head * HD + tx * 4;
#pragma unroll
    for (int i = 0; i < 4; ++i) {
        const int l = ty*4 + i;
        ushort4 hv, lv;
        hv.x = f2bf(o[i][0]); lv.x = f2bf(o[i][0] - bf2f(hv.x));
        hv.y = f2bf(o[i][1]); lv.y = f2bf(o[i][1] - bf2f(hv.y));
        hv.z = f2bf(o[i][2]); lv.z = f2bf(o[i][2] - bf2f(hv.z));
        hv.w = f2bf(o[i][3]); lv.w = f2bf(o[i][3] - bf2f(hv.w));
        *(ushort4*)(dh + (size_t)l * DM) = hv;
        *(ushort4*)(dl + (size_t)l * DM) = lv;
    }
}

// ---------------------------------------------------------------------------
extern "C" void kernel_launch(void* const* d_in, const int* in_sizes, int n_in,
                              void* d_out, int out_size, void* d_ws, size_t ws_size,
                              hipStream_t stream)
{
    const float* x   = (const float*)d_in[0];
    const float* Wq  = (const float*)d_in[1];
    const float* Wk  = (const float*)d_in[2];
    const float* Wv  = (const float*)d_in[3];
    const float* Wo  = (const float*)d_in[4];
    const float* Wb  = (const float*)d_in[5];
    const float* rpb = (const float*)d_in[6];
    const int*   rc  = (const int*)d_in[7];
    float* out = (float*)d_out;

    char* ws = (char*)d_ws;
    unsigned short* Xhi = (unsigned short*)ws;                    // 50,331,648 B
    unsigned short* Xlo = (unsigned short*)(ws + 50331648);       // 50,331,648 B
    float* Qb = (float*)(ws + 100663296);                         // 100,663,296 B
    float* Kb = Qb + 25165824;
    float* Vb = Kb + 25165824;                                    // ends at 402,653,184

    // QKV weight splits live in d_out (scratch until outproj overwrites it).
    unsigned short* Whi = (unsigned short*)d_out;                 // 3,538,944 B
    unsigned short* Wlo = Whi + 1769472;                          // 3,538,944 B
    // Wo splits live in the Q region (dead after attn).
    unsigned short* Wohi = (unsigned short*)Qb;                   // 1,179,648 B
    unsigned short* Wolo = Wohi + 589824;                         // 1,179,648 B

    unsigned short* Obhi = Xhi;    // alias: X dead after qkv_mfma
    unsigned short* Oblo = Xlo;

    xprep_kernel<<<dim3(128, 24, 8), 256, 0, stream>>>(x, Xhi, Xlo);
    fsplit_kernel<<<576, 256, 0, stream>>>(Wq, Whi,           Wlo,           589824);
    fsplit_kernel<<<576, 256, 0, stream>>>(Wk, Whi +  589824, Wlo +  589824, 589824);
    fsplit_kernel<<<576, 256, 0, stream>>>(Wv, Whi + 1179648, Wlo + 1179648, 589824);

    qkv_mfma_kernel<<<dim3(18, 256), 256, 0, stream>>>(Xhi, Xlo, Whi, Wlo,
                                                       Qb, Kb, Vb);
    attn_kernel<<<dim3(NWIN, NHEADS), 256, 0, stream>>>(Qb, Kb, Vb, rpb, rc,
                                                        Obhi, Oblo);
    fsplit_kernel<<<576, 256, 0, stream>>>(Wo, Wohi, Wolo, 589824);
    outproj_mfma_kernel<<<dim3(6, 256), 256, 0, stream>>>(Obhi, Oblo,
                                                          Wohi, Wolo, Wb, out);
}

// Round 8
// 881.775 us; speedup vs baseline: 2.7843x; 1.0204x over previous
//
#include <hip/hip_runtime.h>

// Swin window attention, split-bf16 MFMA everywhere (GEMMs + attention core).
// B=8, DM=768, NH=12, HD=64, H=W=64, WS=8 -> 512 windows x 64 tokens, M=32768.
//
// Pipeline:
//   xprep       : gather x (B,C,H,W) -> Xw[token][c] split into bf16 hi/lo
//   fsplit x3   : [Wq;Wk;Wv] -> bf16 hi/lo  (scratch = d_out, dead until outproj)
//   qkv_mfma    : 3-term split-bf16 MFMA -> Q,K ([win][head][tok][d], bf16 hi/lo,
//                 Q pre-scaled 1/8) and V transposed ([win][head][d][tok] hi/lo)
//   attn_mfma   : per (window,head) wave: S=QK^T+bias (3-term MFMA), softmax,
//                 O=PV (3-term MFMA, P hi/lo via swizzled LDS) -> Obuf hi/lo
//   fsplit (Wo) : Wo -> bf16 hi/lo into Q region (dead after attn)
//   outproj     : split-bf16 MFMA + bias -> out (B,C,H,W)
//
// d_ws map (total exactly 402,653,184 B):
//   [0,          100663296) Xhi|Xlo   (Obuf hi|lo alias after qkv)
//   [100663296,  402653184) Qhi|Qlo|Khi|Klo|Vthi|Vtlo (6 x 50,331,648 B)
//                           (Wo splits alias Qhi after attn)
// d_out doubles as scratch for the QKV W-splits until outproj.

#define DM      768
#define NHEADS  12
#define HD      64
#define LTOK    64
#define NWIN    512

typedef __attribute__((ext_vector_type(8))) short bf16x8;
typedef __attribute__((ext_vector_type(4))) float f32x4;

__device__ __forceinline__ unsigned short f2bf(float f) {
    union { float f; unsigned u; } v; v.f = f;
    unsigned r = v.u + 0x7FFFu + ((v.u >> 16) & 1u);   // RNE
    return (unsigned short)(r >> 16);
}
__device__ __forceinline__ float bf2f(unsigned short h) {
    union { unsigned u; float f; } v; v.u = ((unsigned)h) << 16;
    return v.f;
}
__device__ __forceinline__ void gl_lds16(const void* g, void* l) {
    __builtin_amdgcn_global_load_lds(
        (const __attribute__((address_space(1))) void*)g,
        (__attribute__((address_space(3))) void*)l, 16, 0, 0);
}

// ---------------------------------------------------------------------------
// xprep: 32c x 32px transpose tiles. (unchanged, proven)
// ---------------------------------------------------------------------------
__global__ __launch_bounds__(256)
void xprep_kernel(const float* __restrict__ x,
                  unsigned short* __restrict__ Xhi,
                  unsigned short* __restrict__ Xlo)
{
    __shared__ float lds[32][33];
    const int tid = threadIdx.x;
    const int px0 = blockIdx.x * 32;
    const int c0  = blockIdx.y * 32;
    const int b   = blockIdx.z;
    {
        const int cc = tid >> 3, w4 = tid & 7;
        const float4 v = *(const float4*)(
            x + ((size_t)(b * DM + c0 + cc)) * 4096 + px0 + w4 * 4);
        lds[cc][w4*4+0] = v.x; lds[cc][w4*4+1] = v.y;
        lds[cc][w4*4+2] = v.z; lds[cc][w4*4+3] = v.w;
    }
    __syncthreads();
    const int tpx = tid >> 3, cg = tid & 7;
    const int p = px0 + tpx, h = p >> 6, w = p & 63;
    const int t = (((b << 6) | ((h >> 3) << 3) | (w >> 3)) << 6)
                | ((h & 7) << 3) | (w & 7);
    const size_t dst = (size_t)t * DM + c0 + cg * 4;
    const float f0 = lds[cg*4+0][tpx], f1 = lds[cg*4+1][tpx],
                f2 = lds[cg*4+2][tpx], f3 = lds[cg*4+3][tpx];
    ushort4 hv, lv;
    hv.x = f2bf(f0); lv.x = f2bf(f0 - bf2f(hv.x));
    hv.y = f2bf(f1); lv.y = f2bf(f1 - bf2f(hv.y));
    hv.z = f2bf(f2); lv.z = f2bf(f2 - bf2f(hv.z));
    hv.w = f2bf(f3); lv.w = f2bf(f3 - bf2f(hv.w));
    *(ushort4*)(Xhi + dst) = hv;
    *(ushort4*)(Xlo + dst) = lv;
}

// ---------------------------------------------------------------------------
__global__ __launch_bounds__(256)
void fsplit_kernel(const float* __restrict__ src,
                   unsigned short* __restrict__ hi,
                   unsigned short* __restrict__ lo, int n)
{
    const int i = (blockIdx.x * 256 + threadIdx.x) * 4;
    if (i >= n) return;
    const float4 v = *(const float4*)(src + i);
    ushort4 hv, lv;
    hv.x = f2bf(v.x); lv.x = f2bf(v.x - bf2f(hv.x));
    hv.y = f2bf(v.y); lv.y = f2bf(v.y - bf2f(hv.y));
    hv.z = f2bf(v.z); lv.z = f2bf(v.z - bf2f(hv.z));
    hv.w = f2bf(v.w); lv.w = f2bf(v.w - bf2f(hv.w));
    *(ushort4*)(hi + i) = hv;
    *(ushort4*)(lo + i) = lv;
}

// ---------------------------------------------------------------------------
// Split-bf16 MFMA GEMM prologue (unchanged, proven: MfmaUtil 40%, conflicts 0)
// ---------------------------------------------------------------------------
#define GEMM_PROLOGUE(AHIP, ALOP, BHIP, BLOP)                                  \
    __shared__ f32x4 smem4[2048];           /* 32 KB, 16B-aligned */           \
    char* const smem = (char*)smem4;                                           \
    const int tid  = threadIdx.x;                                              \
    const int lane = tid & 63, wv = tid >> 6;                                  \
    const int wr = wv >> 1, wc = wv & 1;                                       \
    const int nt = blockIdx.x;                                                 \
    const int m0 = blockIdx.y * 128;                                           \
    const int n0 = nt * 128;                                                   \
    const int rql = lane >> 2;                                                 \
    const int gsw = (lane & 3) ^ ((lane >> 3) & 3);                            \
    const char* gb0 = (const char*)(AHIP) + (size_t)m0 * 1536;                 \
    const char* gb1 = (const char*)(ALOP) + (size_t)m0 * 1536;                 \
    const char* gb2 = (const char*)(BHIP) + (size_t)n0 * 1536;                 \
    const char* gb3 = (const char*)(BLOP) + (size_t)n0 * 1536;                 \
    const int l15 = lane & 15, kg = lane >> 4;                                 \
    const int kgp = kg ^ ((l15 >> 1) & 3);                                     \
    int aoff[4], boff[4];                                                      \
    _Pragma("unroll")                                                          \
    for (int f = 0; f < 4; ++f) {                                              \
        aoff[f] = (wr * 64 + f * 16 + l15) * 64 + kgp * 16;                    \
        boff[f] = (wc * 64 + f * 16 + l15) * 64 + kgp * 16;                    \
    }                                                                          \
    f32x4 acc[4][4];                                                           \
    _Pragma("unroll")                                                          \
    for (int i = 0; i < 4; ++i)                                                \
        _Pragma("unroll")                                                      \
        for (int j = 0; j < 4; ++j) acc[i][j] = (f32x4){0.f, 0.f, 0.f, 0.f};   \
    _Pragma("unroll 1")                                                        \
    for (int kt = 0; kt < DM; kt += 32) {                                      \
        const size_t kb = (size_t)kt * 2;                                      \
        _Pragma("unroll")                                                      \
        for (int q = 0; q < 8; ++q) {                                          \
            const int tt = q >> 1;                                             \
            const int s  = wv * 2 + (q & 1);                                   \
            const int r  = s * 16 + rql;                                       \
            const char* srcp = (tt == 0 ? gb0 : tt == 1 ? gb1 :                \
                                tt == 2 ? gb2 : gb3)                           \
                               + (size_t)r * 1536 + kb + gsw * 16;             \
            gl_lds16(srcp, smem + tt * 8192 + s * 1024);                       \
        }                                                                      \
        __syncthreads();                                                       \
        bf16x8 ah[4], al[4], bh[4], bl[4];                                     \
        _Pragma("unroll")                                                      \
        for (int f = 0; f < 4; ++f) {                                          \
            ah[f] = *(const bf16x8*)(smem +     0 + aoff[f]);                  \
            al[f] = *(const bf16x8*)(smem +  8192 + aoff[f]);                  \
            bh[f] = *(const bf16x8*)(smem + 16384 + boff[f]);                  \
            bl[f] = *(const bf16x8*)(smem + 24576 + boff[f]);                  \
        }                                                                      \
        _Pragma("unroll")                                                      \
        for (int mi = 0; mi < 4; ++mi)                                         \
            _Pragma("unroll")                                                  \
            for (int ni = 0; ni < 4; ++ni) {                                   \
                acc[mi][ni] = __builtin_amdgcn_mfma_f32_16x16x32_bf16(         \
                    ah[mi], bh[ni], acc[mi][ni], 0, 0, 0);                     \
                acc[mi][ni] = __builtin_amdgcn_mfma_f32_16x16x32_bf16(         \
                    ah[mi], bl[ni], acc[mi][ni], 0, 0, 0);                     \
                acc[mi][ni] = __builtin_amdgcn_mfma_f32_16x16x32_bf16(         \
                    al[mi], bh[ni], acc[mi][ni], 0, 0, 0);                     \
            }                                                                  \
        __syncthreads();                                                       \
    }

// qkv: epilogue writes split-bf16. Q/K: [win][head][tok][d] (Q pre-scaled);
// V: transposed [win][head][d][tok] (so attn's PV B-fragments are contiguous).
__global__ __launch_bounds__(256, 2)
void qkv_mfma_kernel(const unsigned short* __restrict__ Xhi,
                     const unsigned short* __restrict__ Xlo,
                     const unsigned short* __restrict__ Whi,
                     const unsigned short* __restrict__ Wlo,
                     unsigned short* __restrict__ Qhi,
                     unsigned short* __restrict__ Qlo,
                     unsigned short* __restrict__ Khi,
                     unsigned short* __restrict__ Klo,
                     unsigned short* __restrict__ Vthi,
                     unsigned short* __restrict__ Vtlo)
{
    GEMM_PROLOGUE(Xhi, Xlo, Whi, Wlo)

    const int mat = nt / 6, c6 = nt % 6;
    const int head = c6 * 2 + wc;
    if (mat < 2) {
        unsigned short* __restrict__ Hi = (mat == 0) ? Qhi : Khi;
        unsigned short* __restrict__ Lo = (mat == 0) ? Qlo : Klo;
        const float scale = (mat == 0) ? 0.125f : 1.0f;   // 1/sqrt(64)
#pragma unroll
        for (int mi = 0; mi < 4; ++mi) {
#pragma unroll
            for (int qq = 0; qq < 4; ++qq) {
                const int m   = m0 + wr * 64 + mi * 16 + kg * 4 + qq;
                const int win = m >> 6, tok = m & 63;
                const size_t rb = ((size_t)(win * NHEADS + head) * 64 + tok) * 64;
#pragma unroll
                for (int ni = 0; ni < 4; ++ni) {
                    const int d = ni * 16 + l15;
                    const float f = acc[mi][ni][qq] * scale;
                    const unsigned short h = f2bf(f);
                    Hi[rb + d] = h;
                    Lo[rb + d] = f2bf(f - bf2f(h));
                }
            }
        }
    } else {
        // V transposed: [win][head][d][tok]
#pragma unroll
        for (int mi = 0; mi < 4; ++mi) {
#pragma unroll
            for (int qq = 0; qq < 4; ++qq) {
                const int m   = m0 + wr * 64 + mi * 16 + kg * 4 + qq;
                const int win = m >> 6, tok = m & 63;
                const size_t hb = (size_t)(win * NHEADS + head) * 4096;
#pragma unroll
                for (int ni = 0; ni < 4; ++ni) {
                    const int d = ni * 16 + l15;
                    const float f = acc[mi][ni][qq];
                    const unsigned short h = f2bf(f);
                    const size_t a = hb + (size_t)d * 64 + tok;
                    Vthi[a] = h;
                    Vtlo[a] = f2bf(f - bf2f(h));
                }
            }
        }
    }
}

__global__ __launch_bounds__(256, 2)
void outproj_mfma_kernel(const unsigned short* __restrict__ Ohi,
                         const unsigned short* __restrict__ Olo,
                         const unsigned short* __restrict__ Wohi,
                         const unsigned short* __restrict__ Wolo,
                         const float* __restrict__ Wb,
                         float* __restrict__ out)
{
    GEMM_PROLOGUE(Ohi, Olo, Wohi, Wolo)

    float bsv[4];
    int   ocol[4];
#pragma unroll
    for (int ni = 0; ni < 4; ++ni) {
        ocol[ni] = n0 + wc * 64 + ni * 16 + l15;
        bsv[ni]  = Wb[ocol[ni]];
    }
#pragma unroll
    for (int mi = 0; mi < 4; ++mi) {
#pragma unroll
        for (int qq = 0; qq < 4; ++qq) {
            const int m    = m0 + wr * 64 + mi * 16 + kg * 4 + qq;
            const int win  = m >> 6, tl = m & 63;
            const int bimg = win >> 6, wh = (win >> 3) & 7, ww = win & 7;
            const int h = wh * 8 + (tl >> 3), w = ww * 8 + (tl & 7);
            float* pix = out + (size_t)bimg * DM * 4096 + (size_t)h * 64 + w;
#pragma unroll
            for (int ni = 0; ni < 4; ++ni)
                pix[(size_t)ocol[ni] * 4096] = acc[mi][ni][qq] + bsv[ni];
        }
    }
}

// ---------------------------------------------------------------------------
// attn_mfma: one wave per (window, head). grid (512, 3), block 256 (4 waves).
// Frag maps identical to the verified GEMM family:
//   A-frag: lane l -> A[l&15][8*(l>>4)+j] (16B contiguous from row-major [r][k])
//   B-frag: lane l -> B[8*(l>>4)+j][l&15] (16B contiguous from row-major [c][k])
//   D:      lane l, reg q -> D[4*(l>>4)+q][l&15]
// S = Q K^T: A rows = Q[tok][d], B cols from K[tok][d]   (both natural layout)
// O = P V  : A rows = P[l][m] (LDS, XOR-swizzled), B cols from Vt[d][tok]
// P hi/lo round-trips through 16 KB/wave LDS; swizzle byte^=((row&7)<<4)
// makes the stride-128B ds_read_b128 conflict-free (G4).
// ---------------------------------------------------------------------------
__global__ __launch_bounds__(256, 2)
void attn_mfma_kernel(const unsigned short* __restrict__ Qhi,
                      const unsigned short* __restrict__ Qlo,
                      const unsigned short* __restrict__ Khi,
                      const unsigned short* __restrict__ Klo,
                      const unsigned short* __restrict__ Vthi,
                      const unsigned short* __restrict__ Vtlo,
                      const float* __restrict__ rpb,     // [12][225]
                      const int*   __restrict__ coords,  // [64][64]
                      unsigned short* __restrict__ Obhi,
                      unsigned short* __restrict__ Oblo)
{
    __shared__ f32x4 plds4[4096];                       // 64 KB, 16B-aligned
    char* const pldsb = (char*)plds4;

    const int tid  = threadIdx.x;
    const int lane = tid & 63, wvi = tid >> 6;
    const int l15 = lane & 15, kg = lane >> 4;
    const int win  = blockIdx.x;
    const int head = blockIdx.y * 4 + wvi;
    const size_t base = (size_t)(win * NHEADS + head) * 4096;
    char* const pw = pldsb + wvi * 16384;               // hi @0, lo @8192

    // ---- Q/K fragments straight from global (coalesced 16B per lane) ----
    bf16x8 qh[4][2], ql[4][2], kh[4][2], kl[4][2];
#pragma unroll
    for (int i = 0; i < 4; ++i)
#pragma unroll
        for (int ks = 0; ks < 2; ++ks) {
            const size_t o = base + (size_t)(i * 16 + l15) * 64 + ks * 32 + kg * 8;
            qh[i][ks] = *(const bf16x8*)(Qhi + o);
            ql[i][ks] = *(const bf16x8*)(Qlo + o);
            kh[i][ks] = *(const bf16x8*)(Khi + o);
            kl[i][ks] = *(const bf16x8*)(Klo + o);
        }

    // ---- S = Q K^T, 3-term split ----
    f32x4 s[4][4];
#pragma unroll
    for (int li = 0; li < 4; ++li)
#pragma unroll
        for (int mi = 0; mi < 4; ++mi) s[li][mi] = (f32x4){0.f, 0.f, 0.f, 0.f};
#pragma unroll
    for (int li = 0; li < 4; ++li)
#pragma unroll
        for (int mi = 0; mi < 4; ++mi)
#pragma unroll
            for (int ks = 0; ks < 2; ++ks) {
                s[li][mi] = __builtin_amdgcn_mfma_f32_16x16x32_bf16(
                    qh[li][ks], kh[mi][ks], s[li][mi], 0, 0, 0);
                s[li][mi] = __builtin_amdgcn_mfma_f32_16x16x32_bf16(
                    qh[li][ks], kl[mi][ks], s[li][mi], 0, 0, 0);
                s[li][mi] = __builtin_amdgcn_mfma_f32_16x16x32_bf16(
                    ql[li][ks], kh[mi][ks], s[li][mi], 0, 0, 0);
            }

    // ---- bias + row softmax (rows live in 16-lane groups) + P->LDS ----
    const float* rpbh = rpb + head * 225;
#pragma unroll
    for (int li = 0; li < 4; ++li) {
#pragma unroll
        for (int q = 0; q < 4; ++q) {
            const int r = li * 16 + kg * 4 + q;
            float pv[4];
#pragma unroll
            for (int mi = 0; mi < 4; ++mi)
                pv[mi] = s[li][mi][q] + rpbh[coords[r * 64 + mi * 16 + l15]];
            float mx = fmaxf(fmaxf(pv[0], pv[1]), fmaxf(pv[2], pv[3]));
#pragma unroll
            for (int off = 1; off < 16; off <<= 1)
                mx = fmaxf(mx, __shfl_xor(mx, off));
            float sum = 0.0f;
#pragma unroll
            for (int mi = 0; mi < 4; ++mi) {
                pv[mi] = expf(pv[mi] - mx);
                sum += pv[mi];
            }
#pragma unroll
            for (int off = 1; off < 16; off <<= 1)
                sum += __shfl_xor(sum, off);
            const float inv = 1.0f / sum;
#pragma unroll
            for (int mi = 0; mi < 4; ++mi) {
                const float p = pv[mi] * inv;
                const unsigned short h = f2bf(p);
                const unsigned short l = f2bf(p - bf2f(h));
                const int byt = (r * 128 + (mi * 16 + l15) * 2) ^ ((r & 7) << 4);
                *(unsigned short*)(pw + byt)        = h;
                *(unsigned short*)(pw + 8192 + byt) = l;
            }
        }
    }

    // ---- V fragments from Vt[d][tok] (coalesced 16B per lane) ----
    bf16x8 vh[4][2], vl[4][2];
#pragma unroll
    for (int di = 0; di < 4; ++di)
#pragma unroll
        for (int ks = 0; ks < 2; ++ks) {
            const size_t o = base + (size_t)(di * 16 + l15) * 64 + ks * 32 + kg * 8;
            vh[di][ks] = *(const bf16x8*)(Vthi + o);
            vl[di][ks] = *(const bf16x8*)(Vtlo + o);
        }

    // ---- O = P V, 3-term split; P A-frags via swizzled ds_read_b128 ----
#pragma unroll
    for (int li = 0; li < 4; ++li) {
        bf16x8 ph[2], pl[2];
#pragma unroll
        for (int ks = 0; ks < 2; ++ks) {
            const int row = li * 16 + l15;
            const int byt = (row * 128 + ks * 64 + kg * 16) ^ ((row & 7) << 4);
            ph[ks] = *(const bf16x8*)(pw + byt);
            pl[ks] = *(const bf16x8*)(pw + 8192 + byt);
        }
        f32x4 oacc[4];
#pragma unroll
        for (int di = 0; di < 4; ++di) oacc[di] = (f32x4){0.f, 0.f, 0.f, 0.f};
#pragma unroll
        for (int di = 0; di < 4; ++di)
#pragma unroll
            for (int ks = 0; ks < 2; ++ks) {
                oacc[di] = __builtin_amdgcn_mfma_f32_16x16x32_bf16(
                    ph[ks], vh[di][ks], oacc[di], 0, 0, 0);
                oacc[di] = __builtin_amdgcn_mfma_f32_16x16x32_bf16(
                    ph[ks], vl[di][ks], oacc[di], 0, 0, 0);
                oacc[di] = __builtin_amdgcn_mfma_f32_16x16x32_bf16(
                    pl[ks], vh[di][ks], oacc[di], 0, 0, 0);
            }
        // store O rows of this li: Obuf [win*64+l][head*64+d], hi/lo
#pragma unroll
        for (int q = 0; q < 4; ++q) {
            const int ltok = li * 16 + kg * 4 + q;
            const size_t rb = (size_t)(win * LTOK + ltok) * DM + head * HD;
#pragma unroll
            for (int di = 0; di < 4; ++di) {
                const int d = di * 16 + l15;
                const float f = oacc[di][q];
                const unsigned short h = f2bf(f);
                Obhi[rb + d] = h;
                Oblo[rb + d] = f2bf(f - bf2f(h));
            }
        }
    }
}

// ---------------------------------------------------------------------------
extern "C" void kernel_launch(void* const* d_in, const int* in_sizes, int n_in,
                              void* d_out, int out_size, void* d_ws, size_t ws_size,
                              hipStream_t stream)
{
    const float* x   = (const float*)d_in[0];
    const float* Wq  = (const float*)d_in[1];
    const float* Wk  = (const float*)d_in[2];
    const float* Wv  = (const float*)d_in[3];
    const float* Wo  = (const float*)d_in[4];
    const float* Wb  = (const float*)d_in[5];
    const float* rpb = (const float*)d_in[6];
    const int*   rc  = (const int*)d_in[7];
    float* out = (float*)d_out;

    char* ws = (char*)d_ws;
    unsigned short* Xhi = (unsigned short*)ws;                    // 50,331,648 B
    unsigned short* Xlo = (unsigned short*)(ws + 50331648);       // 50,331,648 B
    // Q/K/V split-bf16 region: 6 x 25,165,824 ushorts, ends at 402,653,184 B.
    unsigned short* Qhi  = (unsigned short*)(ws + 100663296);
    unsigned short* Qlo  = Qhi  + 25165824;
    unsigned short* Khi  = Qlo  + 25165824;
    unsigned short* Klo  = Khi  + 25165824;
    unsigned short* Vthi = Klo  + 25165824;
    unsigned short* Vtlo = Vthi + 25165824;

    // QKV weight splits live in d_out (scratch until outproj overwrites it).
    unsigned short* Whi = (unsigned short*)d_out;                 // 3,538,944 B
    unsigned short* Wlo = Whi + 1769472;                          // 3,538,944 B
    // Wo splits live in the Qhi region (dead after attn).
    unsigned short* Wohi = Qhi;                                   // 1,179,648 B
    unsigned short* Wolo = Wohi + 589824;                         // 1,179,648 B

    unsigned short* Obhi = Xhi;    // alias: X dead after qkv_mfma
    unsigned short* Oblo = Xlo;

    xprep_kernel<<<dim3(128, 24, 8), 256, 0, stream>>>(x, Xhi, Xlo);
    fsplit_kernel<<<576, 256, 0, stream>>>(Wq, Whi,           Wlo,           589824);
    fsplit_kernel<<<576, 256, 0, stream>>>(Wk, Whi +  589824, Wlo +  589824, 589824);
    fsplit_kernel<<<576, 256, 0, stream>>>(Wv, Whi + 1179648, Wlo + 1179648, 589824);

    qkv_mfma_kernel<<<dim3(18, 256), 256, 0, stream>>>(
        Xhi, Xlo, Whi, Wlo, Qhi, Qlo, Khi, Klo, Vthi, Vtlo);
    attn_mfma_kernel<<<dim3(NWIN, 3), 256, 0, stream>>>(
        Qhi, Qlo, Khi, Klo, Vthi, Vtlo, rpb, rc, Obhi, Oblo);
    fsplit_kernel<<<576, 256, 0, stream>>>(Wo, Wohi, Wolo, 589824);
    outproj_mfma_kernel<<<dim3(6, 256), 256, 0, stream>>>(Obhi, Oblo,
                                                          Wohi, Wolo, Wb, out);
}

// Round 10
// 836.708 us; speedup vs baseline: 2.9343x; 1.0539x over previous
//
#include <hip/hip_runtime.h>

// Swin window attention, split-bf16 MFMA everywhere (GEMMs + attention core).
// B=8, DM=768, NH=12, HD=64, H=W=64, WS=8 -> 512 windows x 64 tokens, M=32768.
//
// Pipeline:
//   xprep       : gather x (B,C,H,W) -> Xw[token][c] split into bf16 hi/lo
//   fsplit x3   : [Wq;Wk;Wv] -> bf16 hi/lo  (scratch = d_out, dead until outproj)
//   qkv_mfma    : 3-term split-bf16 MFMA -> Q,K ([win][head][tok][d], bf16 hi/lo,
//                 Q pre-scaled 1/8) and V transposed ([win][head][d][tok] hi/lo,
//                 via in-epilogue LDS transpose -> coalesced ushort8 stores)
//   attn_mfma   : per (window,head) wave: S=QK^T+bias (3-term MFMA), softmax,
//                 O=PV (3-term MFMA, P hi/lo via swizzled LDS) -> Obuf hi/lo
//   fsplit (Wo) : Wo -> bf16 hi/lo into Q region (dead after attn)
//   outproj     : split-bf16 MFMA + bias -> out (B,C,H,W)
//
// d_ws map (total exactly 402,653,184 B):
//   [0,          100663296) Xhi|Xlo   (Obuf hi|lo alias after qkv)
//   [100663296,  402653184) Qhi|Qlo|Khi|Klo|Vthi|Vtlo (6 x 50,331,648 B)
//                           (Wo splits alias Qhi after attn)
// d_out doubles as scratch for the QKV W-splits until outproj.

#define DM      768
#define NHEADS  12
#define HD      64
#define LTOK    64
#define NWIN    512

typedef __attribute__((ext_vector_type(8))) short bf16x8;
typedef __attribute__((ext_vector_type(8))) unsigned short u16x8;
typedef __attribute__((ext_vector_type(4))) float f32x4;

__device__ __forceinline__ unsigned short f2bf(float f) {
    union { float f; unsigned u; } v; v.f = f;
    unsigned r = v.u + 0x7FFFu + ((v.u >> 16) & 1u);   // RNE
    return (unsigned short)(r >> 16);
}
__device__ __forceinline__ float bf2f(unsigned short h) {
    union { unsigned u; float f; } v; v.u = ((unsigned)h) << 16;
    return v.f;
}
__device__ __forceinline__ void gl_lds16(const void* g, void* l) {
    __builtin_amdgcn_global_load_lds(
        (const __attribute__((address_space(1))) void*)g,
        (__attribute__((address_space(3))) void*)l, 16, 0, 0);
}

// ---------------------------------------------------------------------------
// xprep: 32c x 32px transpose tiles. (unchanged, proven)
// ---------------------------------------------------------------------------
__global__ __launch_bounds__(256)
void xprep_kernel(const float* __restrict__ x,
                  unsigned short* __restrict__ Xhi,
                  unsigned short* __restrict__ Xlo)
{
    __shared__ float lds[32][33];
    const int tid = threadIdx.x;
    const int px0 = blockIdx.x * 32;
    const int c0  = blockIdx.y * 32;
    const int b   = blockIdx.z;
    {
        const int cc = tid >> 3, w4 = tid & 7;
        const float4 v = *(const float4*)(
            x + ((size_t)(b * DM + c0 + cc)) * 4096 + px0 + w4 * 4);
        lds[cc][w4*4+0] = v.x; lds[cc][w4*4+1] = v.y;
        lds[cc][w4*4+2] = v.z; lds[cc][w4*4+3] = v.w;
    }
    __syncthreads();
    const int tpx = tid >> 3, cg = tid & 7;
    const int p = px0 + tpx, h = p >> 6, w = p & 63;
    const int t = (((b << 6) | ((h >> 3) << 3) | (w >> 3)) << 6)
                | ((h & 7) << 3) | (w & 7);
    const size_t dst = (size_t)t * DM + c0 + cg * 4;
    const float f0 = lds[cg*4+0][tpx], f1 = lds[cg*4+1][tpx],
                f2 = lds[cg*4+2][tpx], f3 = lds[cg*4+3][tpx];
    ushort4 hv, lv;
    hv.x = f2bf(f0); lv.x = f2bf(f0 - bf2f(hv.x));
    hv.y = f2bf(f1); lv.y = f2bf(f1 - bf2f(hv.y));
    hv.z = f2bf(f2); lv.z = f2bf(f2 - bf2f(hv.z));
    hv.w = f2bf(f3); lv.w = f2bf(f3 - bf2f(hv.w));
    *(ushort4*)(Xhi + dst) = hv;
    *(ushort4*)(Xlo + dst) = lv;
}

// ---------------------------------------------------------------------------
__global__ __launch_bounds__(256)
void fsplit_kernel(const float* __restrict__ src,
                   unsigned short* __restrict__ hi,
                   unsigned short* __restrict__ lo, int n)
{
    const int i = (blockIdx.x * 256 + threadIdx.x) * 4;
    if (i >= n) return;
    const float4 v = *(const float4*)(src + i);
    ushort4 hv, lv;
    hv.x = f2bf(v.x); lv.x = f2bf(v.x - bf2f(hv.x));
    hv.y = f2bf(v.y); lv.y = f2bf(v.y - bf2f(hv.y));
    hv.z = f2bf(v.z); lv.z = f2bf(v.z - bf2f(hv.z));
    hv.w = f2bf(v.w); lv.w = f2bf(v.w - bf2f(hv.w));
    *(ushort4*)(hi + i) = hv;
    *(ushort4*)(lo + i) = lv;
}

// ---------------------------------------------------------------------------
// Split-bf16 MFMA GEMM prologue (unchanged, proven: MfmaUtil 40%, conflicts 0)
// ---------------------------------------------------------------------------
#define GEMM_PROLOGUE(AHIP, ALOP, BHIP, BLOP)                                  \
    __shared__ f32x4 smem4[2048];           /* 32 KB, 16B-aligned */           \
    char* const smem = (char*)smem4;                                           \
    const int tid  = threadIdx.x;                                              \
    const int lane = tid & 63, wv = tid >> 6;                                  \
    const int wr = wv >> 1, wc = wv & 1;                                       \
    const int nt = blockIdx.x;                                                 \
    const int m0 = blockIdx.y * 128;                                           \
    const int n0 = nt * 128;                                                   \
    const int rql = lane >> 2;                                                 \
    const int gsw = (lane & 3) ^ ((lane >> 3) & 3);                            \
    const char* gb0 = (const char*)(AHIP) + (size_t)m0 * 1536;                 \
    const char* gb1 = (const char*)(ALOP) + (size_t)m0 * 1536;                 \
    const char* gb2 = (const char*)(BHIP) + (size_t)n0 * 1536;                 \
    const char* gb3 = (const char*)(BLOP) + (size_t)n0 * 1536;                 \
    const int l15 = lane & 15, kg = lane >> 4;                                 \
    const int kgp = kg ^ ((l15 >> 1) & 3);                                     \
    int aoff[4], boff[4];                                                      \
    _Pragma("unroll")                                                          \
    for (int f = 0; f < 4; ++f) {                                              \
        aoff[f] = (wr * 64 + f * 16 + l15) * 64 + kgp * 16;                    \
        boff[f] = (wc * 64 + f * 16 + l15) * 64 + kgp * 16;                    \
    }                                                                          \
    f32x4 acc[4][4];                                                           \
    _Pragma("unroll")                                                          \
    for (int i = 0; i < 4; ++i)                                                \
        _Pragma("unroll")                                                      \
        for (int j = 0; j < 4; ++j) acc[i][j] = (f32x4){0.f, 0.f, 0.f, 0.f};   \
    _Pragma("unroll 1")                                                        \
    for (int kt = 0; kt < DM; kt += 32) {                                      \
        const size_t kb = (size_t)kt * 2;                                      \
        _Pragma("unroll")                                                      \
        for (int q = 0; q < 8; ++q) {                                          \
            const int tt = q >> 1;                                             \
            const int s  = wv * 2 + (q & 1);                                   \
            const int r  = s * 16 + rql;                                       \
            const char* srcp = (tt == 0 ? gb0 : tt == 1 ? gb1 :                \
                                tt == 2 ? gb2 : gb3)                           \
                               + (size_t)r * 1536 + kb + gsw * 16;             \
            gl_lds16(srcp, smem + tt * 8192 + s * 1024);                       \
        }                                                                      \
        __syncthreads();                                                       \
        bf16x8 ah[4], al[4], bh[4], bl[4];                                     \
        _Pragma("unroll")                                                      \
        for (int f = 0; f < 4; ++f) {                                          \
            ah[f] = *(const bf16x8*)(smem +     0 + aoff[f]);                  \
            al[f] = *(const bf16x8*)(smem +  8192 + aoff[f]);                  \
            bh[f] = *(const bf16x8*)(smem + 16384 + boff[f]);                  \
            bl[f] = *(const bf16x8*)(smem + 24576 + boff[f]);                  \
        }                                                                      \
        _Pragma("unroll")                                                      \
        for (int mi = 0; mi < 4; ++mi)                                         \
            _Pragma("unroll")                                                  \
            for (int ni = 0; ni < 4; ++ni) {                                   \
                acc[mi][ni] = __builtin_amdgcn_mfma_f32_16x16x32_bf16(         \
                    ah[mi], bh[ni], acc[mi][ni], 0, 0, 0);                     \
                acc[mi][ni] = __builtin_amdgcn_mfma_f32_16x16x32_bf16(         \
                    ah[mi], bl[ni], acc[mi][ni], 0, 0, 0);                     \
                acc[mi][ni] = __builtin_amdgcn_mfma_f32_16x16x32_bf16(         \
                    al[mi], bh[ni], acc[mi][ni], 0, 0, 0);                     \
            }                                                                  \
        __syncthreads();                                                       \
    }

// qkv: epilogue writes split-bf16. Q/K: [win][head][tok][d] (Q pre-scaled);
// V: transposed [win][head][d][tok] via LDS transpose + coalesced stores.
__global__ __launch_bounds__(256, 2)
void qkv_mfma_kernel(const unsigned short* __restrict__ Xhi,
                     const unsigned short* __restrict__ Xlo,
                     const unsigned short* __restrict__ Whi,
                     const unsigned short* __restrict__ Wlo,
                     unsigned short* __restrict__ Qhi,
                     unsigned short* __restrict__ Qlo,
                     unsigned short* __restrict__ Khi,
                     unsigned short* __restrict__ Klo,
                     unsigned short* __restrict__ Vthi,
                     unsigned short* __restrict__ Vtlo)
{
    GEMM_PROLOGUE(Xhi, Xlo, Whi, Wlo)

    const int mat = nt / 6, c6 = nt % 6;
    const int head = c6 * 2 + wc;
    if (mat < 2) {
        unsigned short* __restrict__ Hi = (mat == 0) ? Qhi : Khi;
        unsigned short* __restrict__ Lo = (mat == 0) ? Qlo : Klo;
        const float scale = (mat == 0) ? 0.125f : 1.0f;   // 1/sqrt(64)
#pragma unroll
        for (int mi = 0; mi < 4; ++mi) {
#pragma unroll
            for (int qq = 0; qq < 4; ++qq) {
                const int m   = m0 + wr * 64 + mi * 16 + kg * 4 + qq;
                const int win = m >> 6, tok = m & 63;
                const size_t rb = ((size_t)(win * NHEADS + head) * 64 + tok) * 64;
#pragma unroll
                for (int ni = 0; ni < 4; ++ni) {
                    const int d = ni * 16 + l15;
                    const float f = acc[mi][ni][qq] * scale;
                    const unsigned short h = f2bf(f);
                    Hi[rb + d] = h;
                    Lo[rb + d] = f2bf(f - bf2f(h));
                }
            }
        }
    } else {
        // V: the wave's tile is exactly one (window, head) 64tok x 64d block.
        // Old direct scatter (2B stores @ stride 128B) caused L2 partial-line
        // RMW: +106MB FETCH, +66MB WRITE, +60us (R8 counters). Fix: transpose
        // via LDS (smem free after K-loop), then coalesced ushort8 stores.
        // Two passes: wr==0 waves then wr==1, 16KB/wave region by wc.
        // LDS idx = c*64 + (r ^ ((c&7)<<3)): readback conflict-free
        // (d-group lanes cover all 64 slots); writes ~8-way, one-time.
        const int winv = (m0 >> 6) + wr;
        const size_t hb = (size_t)(winv * NHEADS + head) * 4096;
        float* fs = (float*)smem + (wv & 1) * 4096;
        for (int pass = 0; pass < 2; ++pass) {
            if (wr == pass) {
#pragma unroll
                for (int mi = 0; mi < 4; ++mi)
#pragma unroll
                    for (int ni = 0; ni < 4; ++ni)
#pragma unroll
                        for (int qq = 0; qq < 4; ++qq) {
                            const int c = ni * 16 + l15;
                            const int r = mi * 16 + kg * 4 + qq;
                            fs[c * 64 + (r ^ ((c & 7) << 3))] = acc[mi][ni][qq];
                        }
#pragma unroll
                for (int it = 0; it < 8; ++it) {
                    const int d  = it * 8 + (lane >> 3);
                    const int t0 = (lane & 7) * 8;
                    const float* rp = fs + d * 64 + (t0 ^ ((d & 7) << 3));
                    u16x8 hv, lv;
#pragma unroll
                    for (int j = 0; j < 8; ++j) {
                        const float f = rp[j];
                        const unsigned short h = f2bf(f);
                        hv[j] = h;
                        lv[j] = f2bf(f - bf2f(h));
                    }
                    *(u16x8*)(Vthi + hb + (size_t)d * 64 + t0) = hv;
                    *(u16x8*)(Vtlo + hb + (size_t)d * 64 + t0) = lv;
                }
            }
            __syncthreads();
        }
    }
}

__global__ __launch_bounds__(256, 2)
void outproj_mfma_kernel(const unsigned short* __restrict__ Ohi,
                         const unsigned short* __restrict__ Olo,
                         const unsigned short* __restrict__ Wohi,
                         const unsigned short* __restrict__ Wolo,
                         const float* __restrict__ Wb,
                         float* __restrict__ out)
{
    GEMM_PROLOGUE(Ohi, Olo, Wohi, Wolo)

    float bsv[4];
    int   ocol[4];
#pragma unroll
    for (int ni = 0; ni < 4; ++ni) {
        ocol[ni] = n0 + wc * 64 + ni * 16 + l15;
        bsv[ni]  = Wb[ocol[ni]];
    }
#pragma unroll
    for (int mi = 0; mi < 4; ++mi) {
#pragma unroll
        for (int qq = 0; qq < 4; ++qq) {
            const int m    = m0 + wr * 64 + mi * 16 + kg * 4 + qq;
            const int win  = m >> 6, tl = m & 63;
            const int bimg = win >> 6, wh = (win >> 3) & 7, ww = win & 7;
            const int h = wh * 8 + (tl >> 3), w = ww * 8 + (tl & 7);
            float* pix = out + (size_t)bimg * DM * 4096 + (size_t)h * 64 + w;
#pragma unroll
            for (int ni = 0; ni < 4; ++ni)
                pix[(size_t)ocol[ni] * 4096] = acc[mi][ni][qq] + bsv[ni];
        }
    }
}

// ---------------------------------------------------------------------------
// attn_mfma: one wave per (window, head). grid (512, 3), block 256 (4 waves).
// (unchanged from R8 — proven passing; frag maps = verified GEMM family)
// ---------------------------------------------------------------------------
__global__ __launch_bounds__(256, 2)
void attn_mfma_kernel(const unsigned short* __restrict__ Qhi,
                      const unsigned short* __restrict__ Qlo,
                      const unsigned short* __restrict__ Khi,
                      const unsigned short* __restrict__ Klo,
                      const unsigned short* __restrict__ Vthi,
                      const unsigned short* __restrict__ Vtlo,
                      const float* __restrict__ rpb,     // [12][225]
                      const int*   __restrict__ coords,  // [64][64]
                      unsigned short* __restrict__ Obhi,
                      unsigned short* __restrict__ Oblo)
{
    __shared__ f32x4 plds4[4096];                       // 64 KB, 16B-aligned
    char* const pldsb = (char*)plds4;

    const int tid  = threadIdx.x;
    const int lane = tid & 63, wvi = tid >> 6;
    const int l15 = lane & 15, kg = lane >> 4;
    const int win  = blockIdx.x;
    const int head = blockIdx.y * 4 + wvi;
    const size_t base = (size_t)(win * NHEADS + head) * 4096;
    char* const pw = pldsb + wvi * 16384;               // hi @0, lo @8192

    // ---- Q/K fragments straight from global (coalesced 16B per lane) ----
    bf16x8 qh[4][2], ql[4][2], kh[4][2], kl[4][2];
#pragma unroll
    for (int i = 0; i < 4; ++i)
#pragma unroll
        for (int ks = 0; ks < 2; ++ks) {
            const size_t o = base + (size_t)(i * 16 + l15) * 64 + ks * 32 + kg * 8;
            qh[i][ks] = *(const bf16x8*)(Qhi + o);
            ql[i][ks] = *(const bf16x8*)(Qlo + o);
            kh[i][ks] = *(const bf16x8*)(Khi + o);
            kl[i][ks] = *(const bf16x8*)(Klo + o);
        }

    // ---- S = Q K^T, 3-term split ----
    f32x4 s[4][4];
#pragma unroll
    for (int li = 0; li < 4; ++li)
#pragma unroll
        for (int mi = 0; mi < 4; ++mi) s[li][mi] = (f32x4){0.f, 0.f, 0.f, 0.f};
#pragma unroll
    for (int li = 0; li < 4; ++li)
#pragma unroll
        for (int mi = 0; mi < 4; ++mi)
#pragma unroll
            for (int ks = 0; ks < 2; ++ks) {
                s[li][mi] = __builtin_amdgcn_mfma_f32_16x16x32_bf16(
                    qh[li][ks], kh[mi][ks], s[li][mi], 0, 0, 0);
                s[li][mi] = __builtin_amdgcn_mfma_f32_16x16x32_bf16(
                    qh[li][ks], kl[mi][ks], s[li][mi], 0, 0, 0);
                s[li][mi] = __builtin_amdgcn_mfma_f32_16x16x32_bf16(
                    ql[li][ks], kh[mi][ks], s[li][mi], 0, 0, 0);
            }

    // ---- bias + row softmax (rows live in 16-lane groups) + P->LDS ----
    const float* rpbh = rpb + head * 225;
#pragma unroll
    for (int li = 0; li < 4; ++li) {
#pragma unroll
        for (int q = 0; q < 4; ++q) {
            const int r = li * 16 + kg * 4 + q;
            float pv[4];
#pragma unroll
            for (int mi = 0; mi < 4; ++mi)
                pv[mi] = s[li][mi][q] + rpbh[coords[r * 64 + mi * 16 + l15]];
            float mx = fmaxf(fmaxf(pv[0], pv[1]), fmaxf(pv[2], pv[3]));
#pragma unroll
            for (int off = 1; off < 16; off <<= 1)
                mx = fmaxf(mx, __shfl_xor(mx, off));
            float sum = 0.0f;
#pragma unroll
            for (int mi = 0; mi < 4; ++mi) {
                pv[mi] = expf(pv[mi] - mx);
                sum += pv[mi];
            }
#pragma unroll
            for (int off = 1; off < 16; off <<= 1)
                sum += __shfl_xor(sum, off);
            const float inv = 1.0f / sum;
#pragma unroll
            for (int mi = 0; mi < 4; ++mi) {
                const float p = pv[mi] * inv;
                const unsigned short h = f2bf(p);
                const unsigned short l = f2bf(p - bf2f(h));
                const int byt = (r * 128 + (mi * 16 + l15) * 2) ^ ((r & 7) << 4);
                *(unsigned short*)(pw + byt)        = h;
                *(unsigned short*)(pw + 8192 + byt) = l;
            }
        }
    }

    // ---- V fragments from Vt[d][tok] (coalesced 16B per lane) ----
    bf16x8 vh[4][2], vl[4][2];
#pragma unroll
    for (int di = 0; di < 4; ++di)
#pragma unroll
        for (int ks = 0; ks < 2; ++ks) {
            const size_t o = base + (size_t)(di * 16 + l15) * 64 + ks * 32 + kg * 8;
            vh[di][ks] = *(const bf16x8*)(Vthi + o);
            vl[di][ks] = *(const bf16x8*)(Vtlo + o);
        }

    // ---- O = P V, 3-term split; P A-frags via swizzled ds_read_b128 ----
#pragma unroll
    for (int li = 0; li < 4; ++li) {
        bf16x8 ph[2], pl[2];
#pragma unroll
        for (int ks = 0; ks < 2; ++ks) {
            const int row = li * 16 + l15;
            const int byt = (row * 128 + ks * 64 + kg * 16) ^ ((row & 7) << 4);
            ph[ks] = *(const bf16x8*)(pw + byt);
            pl[ks] = *(const bf16x8*)(pw + 8192 + byt);
        }
        f32x4 oacc[4];
#pragma unroll
        for (int di = 0; di < 4; ++di) oacc[di] = (f32x4){0.f, 0.f, 0.f, 0.f};
#pragma unroll
        for (int di = 0; di < 4; ++di)
#pragma unroll
            for (int ks = 0; ks < 2; ++ks) {
                oacc[di] = __builtin_amdgcn_mfma_f32_16x16x32_bf16(
                    ph[ks], vh[di][ks], oacc[di], 0, 0, 0);
                oacc[di] = __builtin_amdgcn_mfma_f32_16x16x32_bf16(
                    ph[ks], vl[di][ks], oacc[di], 0, 0, 0);
                oacc[di] = __builtin_amdgcn_mfma_f32_16x16x32_bf16(
                    pl[ks], vh[di][ks], oacc[di], 0, 0, 0);
            }
        // store O rows of this li: Obuf [win*64+l][head*64+d], hi/lo
#pragma unroll
        for (int q = 0; q < 4; ++q) {
            const int ltok = li * 16 + kg * 4 + q;
            const size_t rb = (size_t)(win * LTOK + ltok) * DM + head * HD;
#pragma unroll
            for (int di = 0; di < 4; ++di) {
                const int d = di * 16 + l15;
                const float f = oacc[di][q];
                const unsigned short h = f2bf(f);
                Obhi[rb + d] = h;
                Oblo[rb + d] = f2bf(f - bf2f(h));
            }
        }
    }
}

// ---------------------------------------------------------------------------
extern "C" void kernel_launch(void* const* d_in, const int* in_sizes, int n_in,
                              void* d_out, int out_size, void* d_ws, size_t ws_size,
                              hipStream_t stream)
{
    const float* x   = (const float*)d_in[0];
    const float* Wq  = (const float*)d_in[1];
    const float* Wk  = (const float*)d_in[2];
    const float* Wv  = (const float*)d_in[3];
    const float* Wo  = (const float*)d_in[4];
    const float* Wb  = (const float*)d_in[5];
    const float* rpb = (const float*)d_in[6];
    const int*   rc  = (const int*)d_in[7];
    float* out = (float*)d_out;

    char* ws = (char*)d_ws;
    unsigned short* Xhi = (unsigned short*)ws;                    // 50,331,648 B
    unsigned short* Xlo = (unsigned short*)(ws + 50331648);       // 50,331,648 B
    // Q/K/V split-bf16 region: 6 x 25,165,824 ushorts, ends at 402,653,184 B.
    unsigned short* Qhi  = (unsigned short*)(ws + 100663296);
    unsigned short* Qlo  = Qhi  + 25165824;
    unsigned short* Khi  = Qlo  + 25165824;
    unsigned short* Klo  = Khi  + 25165824;
    unsigned short* Vthi = Klo  + 25165824;
    unsigned short* Vtlo = Vthi + 25165824;

    // QKV weight splits live in d_out (scratch until outproj overwrites it).
    unsigned short* Whi = (unsigned short*)d_out;                 // 3,538,944 B
    unsigned short* Wlo = Whi + 1769472;                          // 3,538,944 B
    // Wo splits live in the Qhi region (dead after attn).
    unsigned short* Wohi = Qhi;                                   // 1,179,648 B
    unsigned short* Wolo = Wohi + 589824;                         // 1,179,648 B

    unsigned short* Obhi = Xhi;    // alias: X dead after qkv_mfma
    unsigned short* Oblo = Xlo;

    xprep_kernel<<<dim3(128, 24, 8), 256, 0, stream>>>(x, Xhi, Xlo);
    fsplit_kernel<<<576, 256, 0, stream>>>(Wq, Whi,           Wlo,           589824);
    fsplit_kernel<<<576, 256, 0, stream>>>(Wk, Whi +  589824, Wlo +  589824, 589824);
    fsplit_kernel<<<576, 256, 0, stream>>>(Wv, Whi + 1179648, Wlo + 1179648, 589824);

    qkv_mfma_kernel<<<dim3(18, 256), 256, 0, stream>>>(
        Xhi, Xlo, Whi, Wlo, Qhi, Qlo, Khi, Klo, Vthi, Vtlo);
    attn_mfma_kernel<<<dim3(NWIN, 3), 256, 0, stream>>>(
        Qhi, Qlo, Khi, Klo, Vthi, Vtlo, rpb, rc, Obhi, Oblo);
    fsplit_kernel<<<576, 256, 0, stream>>>(Wo, Wohi, Wolo, 589824);
    outproj_mfma_kernel<<<dim3(6, 256), 256, 0, stream>>>(Obhi, Oblo,
                                                          Wohi, Wolo, Wb, out);
}